// Round 1
// baseline (140.507 us; speedup 1.0000x reference)
//
#include <hip/hip_runtime.h>

#define N_EL   15
#define NPAIR  105     // 15*14/2 unique pairs
#define BASIS  64
#define CUTOFF 10.0f
#define LOG_HALF (-0.69314718055994531f)

// shifted softplus: log(0.5 + 0.5*e^x), numerically stable
__device__ __forceinline__ float ssp(float x) {
    float t = __expf(-fabsf(x));
    return fmaxf(x, 0.0f) + __logf(1.0f + t) + LOG_HALF;
}

__global__ __launch_bounds__(128)
void backflow_kernel(const float* __restrict__ rs,
                     const float* __restrict__ W0,
                     const float* __restrict__ b0,
                     const float* __restrict__ W1,
                     const float* __restrict__ b1,
                     const float* __restrict__ W2,
                     float* __restrict__ out) {
    __shared__ float2 s_mi[BASIS];        // (mu, 1/sigma^2)
    __shared__ float  s_xs[N_EL * 3];     // current coordinates
    __shared__ float  s_wd[NPAIR * 3];    // per unique pair: w * diff

    const int tid  = threadIdx.x;
    const int bid  = blockIdx.x;
    const int b    = bid >> 1;            // batch
    const int s    = bid & 1;             // spin block
    const int base = b * (2 * N_EL * 3) + s * (N_EL * 3);

    // distance-basis constants: qs[d] = (2d+1)/128
    if (tid < BASIS) {
        float q  = (float)(2 * tid + 1) * (1.0f / 128.0f);
        float mu = CUTOFF * q * q;
        float sg = fmaf(CUTOFF, q, 1.0f) * (1.0f / 7.0f);
        s_mi[tid] = make_float2(mu, 1.0f / (sg * sg));
    }
    if (tid < N_EL * 3) s_xs[tid] = rs[base + tid];

    // decode unique pair (pi < pj) from tid (row-major upper triangle)
    int pi = 0, pj = 0;
    if (tid < NPAIR) {
        int t = tid, i = 0;
        while (t >= (N_EL - 1 - i)) { t -= (N_EL - 1 - i); ++i; }
        pi = i; pj = i + 1 + t;
    }
    __syncthreads();

    for (int k = 0; k < 3; ++k) {
        const float* W0k = W0 + k * BASIS * 16;
        const float* b0k = b0 + k * 16;
        const float* W1k = W1 + k * 16 * 4;
        const float* b1k = b1 + k * 4;
        const float* W2k = W2 + k * 4;

        if (tid < NPAIR) {
            float dx = s_xs[pj * 3 + 0] - s_xs[pi * 3 + 0];
            float dy = s_xs[pj * 3 + 1] - s_xs[pi * 3 + 1];
            float dz = s_xs[pj * 3 + 2] - s_xs[pi * 3 + 2];
            float dist = sqrtf(fmaf(dx, dx, fmaf(dy, dy, dz * dz)));

            float x = dist * (1.0f / CUTOFF);
            float env = 0.0f;
            if (x <= 1.0f) {
                float p = fmaf(-6.0f, x, 15.0f);
                p = fmaf(p, x, -10.0f);
                float x3 = x * x * x;
                env = fmaf(x3, p, 1.0f);   // 1 - 10x^3 + 15x^4 - 6x^5
            }

            float h1[16];
            #pragma unroll
            for (int c = 0; c < 16; ++c) h1[c] = b0k[c];   // uniform -> s_load

            if (env > 0.0f) {
                #pragma unroll 4
                for (int d = 0; d < BASIS; ++d) {
                    float2 mi = s_mi[d];                    // LDS broadcast
                    float t  = dist - mi.x;
                    float ev = env * __expf(-(t * t) * mi.y);
                    #pragma unroll
                    for (int c = 0; c < 16; ++c)
                        h1[c] = fmaf(ev, W0k[d * 16 + c], h1[c]);  // uniform weights
                }
            }

            float h2[4];
            #pragma unroll
            for (int e2 = 0; e2 < 4; ++e2) h2[e2] = b1k[e2];
            #pragma unroll
            for (int c = 0; c < 16; ++c) {
                float hc = ssp(h1[c]);
                #pragma unroll
                for (int e2 = 0; e2 < 4; ++e2)
                    h2[e2] = fmaf(hc, W1k[c * 4 + e2], h2[e2]);
            }
            float w = 0.0f;
            #pragma unroll
            for (int e2 = 0; e2 < 4; ++e2) w = fmaf(ssp(h2[e2]), W2k[e2], w);

            s_wd[tid * 3 + 0] = w * dx;
            s_wd[tid * 3 + 1] = w * dy;
            s_wd[tid * 3 + 2] = w * dz;
        }
        __syncthreads();

        // scatter-reduce: electron e gets +w*diff for pairs (e,j>e), -w*diff for (i<e,e)
        if (tid < N_EL * 3) {
            int e = tid / 3, dim = tid - 3 * e;
            float acc = 0.0f;
            int offe = e * (2 * N_EL - e - 1) / 2;
            for (int j = e + 1; j < N_EL; ++j)
                acc += s_wd[(offe + j - e - 1) * 3 + dim];
            for (int i2 = 0; i2 < e; ++i2) {
                int p = i2 * (2 * N_EL - i2 - 1) / 2 + (e - i2 - 1);
                acc -= s_wd[p * 3 + dim];
            }
            s_xs[tid] += acc;
        }
        __syncthreads();
    }

    if (tid < N_EL * 3) out[base + tid] = s_xs[tid];
}

extern "C" void kernel_launch(void* const* d_in, const int* in_sizes, int n_in,
                              void* d_out, int out_size, void* d_ws, size_t ws_size,
                              hipStream_t stream) {
    const float* rs = (const float*)d_in[0];
    const float* W0 = (const float*)d_in[1];
    const float* b0 = (const float*)d_in[2];
    const float* W1 = (const float*)d_in[3];
    const float* b1 = (const float*)d_in[4];
    const float* W2 = (const float*)d_in[5];
    float* out = (float*)d_out;

    dim3 grid(4096 * 2);
    dim3 block(128);
    hipLaunchKernelGGL(backflow_kernel, grid, block, 0, stream,
                       rs, W0, b0, W1, b1, W2, out);
}

// Round 2
// 131.337 us; speedup vs baseline: 1.0698x; 1.0698x over previous
//
#include <hip/hip_runtime.h>

#define N_EL   15
#define NPAIR  105     // 15*14/2 unique pairs
#define BASIS  64
#define CUTOFF 10.0f
#define LOG_HALF (-0.69314718055994531f)
#define LOG2E    1.44269504088896340736f
#define PPB    3       // problems per block
#define NTHR   320     // 5 waves; 3*105 = 315 pair threads active (98.4%)

// shifted softplus: log(0.5 + 0.5*e^x), numerically stable
__device__ __forceinline__ float ssp(float x) {
    float t = __builtin_amdgcn_exp2f(-fabsf(x) * LOG2E);   // e^-|x|
    return fmaxf(x, 0.0f) + __logf(1.0f + t) + LOG_HALF;
}

__global__ __launch_bounds__(NTHR, 4)
void backflow_kernel(const float* __restrict__ rs,
                     const float* __restrict__ W0,
                     const float* __restrict__ b0,
                     const float* __restrict__ W1,
                     const float* __restrict__ b1,
                     const float* __restrict__ W2,
                     float* __restrict__ out, int nprob) {
    __shared__ float2 s_mi[BASIS];                 // (mu, -log2e/sigma^2)
    __shared__ float  s_xs[PPB][N_EL * 3];         // coordinates
    __shared__ float  s_wd[PPB][NPAIR * 3];        // per unique pair: w * diff

    const int tid = threadIdx.x;

    // distance-basis constants: qs[d] = (2d+1)/128
    if (tid < BASIS) {
        float q  = (float)(2 * tid + 1) * (1.0f / 128.0f);
        float mu = CUTOFF * q * q;
        float sg = fmaf(CUTOFF, q, 1.0f) * (1.0f / 7.0f);
        s_mi[tid] = make_float2(mu, -LOG2E / (sg * sg));
    }

    // coordinate staging: threads 0..134 load 45 floats for each of 3 problems
    const int q2 = tid / 45, e3 = tid - 45 * q2;
    const int P2 = blockIdx.x * PPB + q2;
    const bool io_ok = (tid < PPB * 45) && (P2 < nprob);
    if (io_ok) s_xs[q2][e3] = rs[P2 * 45 + e3];

    // pair work mapping: thread -> (problem q, unique pair pr)
    const int q  = tid / NPAIR;
    const int pr = tid - NPAIR * q;
    const bool valid = (q < PPB) && (blockIdx.x * PPB + q < nprob);

    // decode unique pair (pi < pj) from pr (row-major upper triangle)
    int pi = 0, pj = 0;
    {
        int t = pr, i = 0;
        while (t >= (N_EL - 1 - i)) { t -= (N_EL - 1 - i); ++i; }
        pi = i; pj = i + 1 + t;
    }
    __syncthreads();

    for (int k = 0; k < 3; ++k) {
        const float* W0k = W0 + k * BASIS * 16;
        const float* b0k = b0 + k * 16;
        const float* W1k = W1 + k * 16 * 4;
        const float* b1k = b1 + k * 4;
        const float* W2k = W2 + k * 4;

        if (valid) {
            float dx = s_xs[q][pj * 3 + 0] - s_xs[q][pi * 3 + 0];
            float dy = s_xs[q][pj * 3 + 1] - s_xs[q][pi * 3 + 1];
            float dz = s_xs[q][pj * 3 + 2] - s_xs[q][pi * 3 + 2];
            float dist = sqrtf(fmaf(dx, dx, fmaf(dy, dy, dz * dz)));

            float x = dist * (1.0f / CUTOFF);
            float env = 0.0f;
            if (x <= 1.0f) {
                float p = fmaf(-6.0f, x, 15.0f);
                p = fmaf(p, x, -10.0f);
                env = fmaf(x * x * x, p, 1.0f);   // 1 - 10x^3 + 15x^4 - 6x^5
            }

            float g[16];
            #pragma unroll
            for (int c = 0; c < 16; ++c) g[c] = 0.0f;

            if (env > 0.0f) {
                #pragma unroll 4
                for (int d = 0; d < BASIS; ++d) {
                    float2 mi = s_mi[d];                    // LDS broadcast
                    float t  = dist - mi.x;
                    float ev = __builtin_amdgcn_exp2f((t * t) * mi.y);
                    #pragma unroll
                    for (int c = 0; c < 16; ++c)
                        g[c] = fmaf(ev, W0k[d * 16 + c], g[c]);  // uniform weights
                }
            }

            float h2[4];
            #pragma unroll
            for (int e2 = 0; e2 < 4; ++e2) h2[e2] = b1k[e2];
            #pragma unroll
            for (int c = 0; c < 16; ++c) {
                float hc = ssp(fmaf(env, g[c], b0k[c]));
                #pragma unroll
                for (int e2 = 0; e2 < 4; ++e2)
                    h2[e2] = fmaf(hc, W1k[c * 4 + e2], h2[e2]);
            }
            float w = 0.0f;
            #pragma unroll
            for (int e2 = 0; e2 < 4; ++e2) w = fmaf(ssp(h2[e2]), W2k[e2], w);

            s_wd[q][pr * 3 + 0] = w * dx;
            s_wd[q][pr * 3 + 1] = w * dy;
            s_wd[q][pr * 3 + 2] = w * dz;
        }
        __syncthreads();

        // scatter-reduce: electron e gets +w*diff for (e,j>e), -w*diff for (i<e,e)
        if (io_ok) {
            int e = e3 / 3, dim = e3 - 3 * e;
            float acc = 0.0f;
            int offe = e * (2 * N_EL - e - 1) / 2;
            for (int j = e + 1; j < N_EL; ++j)
                acc += s_wd[q2][(offe + j - e - 1) * 3 + dim];
            for (int i2 = 0; i2 < e; ++i2) {
                int p = i2 * (2 * N_EL - i2 - 1) / 2 + (e - i2 - 1);
                acc -= s_wd[q2][p * 3 + dim];
            }
            s_xs[q2][e3] += acc;
        }
        __syncthreads();
    }

    if (io_ok) out[P2 * 45 + e3] = s_xs[q2][e3];
}

extern "C" void kernel_launch(void* const* d_in, const int* in_sizes, int n_in,
                              void* d_out, int out_size, void* d_ws, size_t ws_size,
                              hipStream_t stream) {
    const float* rs = (const float*)d_in[0];
    const float* W0 = (const float*)d_in[1];
    const float* b0 = (const float*)d_in[2];
    const float* W1 = (const float*)d_in[3];
    const float* b1 = (const float*)d_in[4];
    const float* W2 = (const float*)d_in[5];
    float* out = (float*)d_out;

    const int nprob = 4096 * 2;                 // (batch, spin) problems
    dim3 grid((nprob + PPB - 1) / PPB);
    dim3 block(NTHR);
    hipLaunchKernelGGL(backflow_kernel, grid, block, 0, stream,
                       rs, W0, b0, W1, b1, W2, out, nprob);
}